// Round 9
// baseline (124.968 us; speedup 1.0000x reference)
//
#include <hip/hip_runtime.h>
#include <math.h>

#define BB 16
#define CIN 64
#define HH 64
#define WW 64
#define COUT 128
#define HW 4096          // HH*WW
#define CK 576           // CIN*9
#define CKP 584          // LDS stride (shorts) for val

#define WROWS 7
#define WCOLS 40
#define NCHUNK 35        // (7*40*128B) / 1024B

typedef __attribute__((ext_vector_type(8))) short short8;
typedef __attribute__((ext_vector_type(4))) short short4v;
typedef __attribute__((ext_vector_type(4))) float f32x4;

// ---- workspace layout (float indices) ----
#define OFF_OFF   0                         // B*18*HW  = 1179648 floats
#define MASK_OFF  1179648                   // B*9*HW   = 589824 floats
#define WT_OFF    1769472                   // wt2: 18*128*32 shorts = 36864 floats
#define WPM_OFF   1806336                   // wpm2: 18*32*32 shorts = 9216 floats
#define XH_OFF    1815552                   // B*HW*CIN shorts = 8388608 floats
#define SAB_OFF   10204160                  // 256 floats
#define STAT_OFF  10204416                  // 256 floats

#define GLOAD_LDS16(gsrc, ldst) \
    __builtin_amdgcn_global_load_lds((const __attribute__((address_space(1))) void*)(gsrc), \
                                     (__attribute__((address_space(3))) void*)(ldst), 16, 0, 0)

__device__ __forceinline__ short f2bf(float f) {
    union { float f; unsigned u; } cv; cv.f = f;
    unsigned u = cv.u;
    unsigned r = (u + 0x7fffu + ((u >> 16) & 1u)) >> 16;
    return (short)r;
}
__device__ __forceinline__ float bf2f(short s) {
    union { unsigned u; float f; } cv;
    cv.u = ((unsigned)(unsigned short)s) << 16;
    return cv.f;
}

// ---------------------------------------------------------------------------
// Kernel A: transpose x NCHW -> NHWC bf16 (xh[b][y][x][c])
__global__ __launch_bounds__(256) void k_nhwc(const float* __restrict__ x,
                                              short* __restrict__ xh) {
    __shared__ float t[64][65];
    const int blk  = blockIdx.x;
    const int b    = blk >> 6;
    const int pos0 = (blk & 63) << 6;
    const int a    = threadIdx.x & 63;
    const int q    = threadIdx.x >> 6;
#pragma unroll
    for (int i = 0; i < 16; ++i) {
        int c = i * 4 + q;
        t[c][a] = x[((size_t)(b * CIN + c)) * HW + pos0 + a];
    }
    __syncthreads();
#pragma unroll
    for (int i = 0; i < 16; ++i) {
        int p = i * 4 + q;
        xh[((size_t)b * HW + pos0 + p) * CIN + a] = f2bf(t[a][p]);
    }
}

// ---------------------------------------------------------------------------
// Kernel B: pack weights to bf16, K-MAJOR panels.
__global__ __launch_bounds__(256) void k_pack(const float* __restrict__ wd,
                                              const float* __restrict__ wp,
                                              const float* __restrict__ wm,
                                              short* __restrict__ wt2,
                                              short* __restrict__ wpm2) {
    int i = blockIdx.x * 256 + threadIdx.x;
    if (i < 18 * 128 * 32) {
        int kc  = i >> 12;
        int rem = i & 4095;
        int co  = rem >> 5;
        int kl  = rem & 31;
        int kk  = kc * 32 + kl;
        int k   = kk >> 6;
        int c   = kk & 63;
        wt2[i] = f2bf(wd[co * CK + c * 9 + k]);
        return;
    }
    i -= 18 * 128 * 32;
    if (i < 18 * 32 * 32) {
        int kc  = i >> 10;
        int rem = i & 1023;
        int t   = rem >> 5;
        int kl  = rem & 31;
        int kk  = kc * 32 + kl;
        int k   = kk >> 6;
        int c   = kk & 63;
        float v = 0.f;
        if (t < 18)      v = wp[t * CK + c * 9 + k];
        else if (t < 27) v = wm[(t - 18) * CK + c * 9 + k];
        wpm2[i] = f2bf(v);
    }
}

// ---------------------------------------------------------------------------
// conv_pm A-fragment loader
__device__ __forceinline__ short8 conv_a(const short* __restrict__ xb,
                                         int ho, int wo, int lk, int kc) {
    const int k  = kc >> 1;
    const int c0 = (kc & 1) * 32 + lk * 8;
    const int yy = ho - 1 + k / 3;
    const int xx = wo - 1 + k % 3;
    const bool valid = ((unsigned)yy < 64u) & ((unsigned)xx < 64u);
    const int yyc = min(max(yy, 0), 63);
    const int xxc = min(max(xx, 0), 63);
    short8 a = *(const short8*)&xb[(((yyc << 6) + xxc) << 6) + c0];
    if (!valid) a = (short8)0;
    return a;
}

// ---------------------------------------------------------------------------
// Kernel 1: offset/mask conv (implicit MFMA GEMM, register-array fragments)
__global__ __launch_bounds__(256) void k_conv_pm(const short* __restrict__ xh,
                                                 const short* __restrict__ wpm2,
                                                 const float* __restrict__ bp,
                                                 const float* __restrict__ bm,
                                                 float* __restrict__ off,
                                                 float* __restrict__ mask) {
    const int bid  = blockIdx.x;
    const int swz  = (bid & 7) * 256 + (bid >> 3);
    const int pos0 = swz * 32;
    const int b   = pos0 >> 12;
    const int ho  = (pos0 >> 6) & 63;
    const int wo0 = pos0 & 63;

    const int tid  = threadIdx.x;
    const int wv   = tid >> 6;
    const int lane = tid & 63;
    const int l15  = lane & 15;
    const int lk   = lane >> 4;
    const int mw   = wv & 1;
    const int nw   = wv >> 1;

    const int p    = mw * 16 + l15;
    const int wo   = wo0 + p;
    const int t    = nw * 16 + l15;

    const short* xb  = xh + (size_t)b * HW * CIN;
    const short* wr  = wpm2 + t * 32 + lk * 8;

    short8 ar[18], brr[18];
#pragma unroll
    for (int kc = 0; kc < 18; ++kc) {
        ar[kc]  = conv_a(xb, ho, wo, lk, kc);
        brr[kc] = *(const short8*)&wr[kc * 1024];
    }
    f32x4 acc = (f32x4)(0.f);
#pragma unroll
    for (int kc = 0; kc < 18; ++kc)
        acc = __builtin_amdgcn_mfma_f32_16x16x32_bf16(ar[kc], brr[kc], acc, 0, 0, 0);

    const int pst = wo0 + mw * 16 + lk * 4;
    if (t < 18) {
        float bias = bp[t];
        float4 o;
        o.x = acc[0] + bias; o.y = acc[1] + bias;
        o.z = acc[2] + bias; o.w = acc[3] + bias;
        *(float4*)&off[(((size_t)b * 18 + t) * HH + ho) * WW + pst] = o;
    } else if (t < 27) {
        float bias = bm[t - 18];
        float4 o;
        o.x = 1.f / (1.f + expf(-(acc[0] + bias)));
        o.y = 1.f / (1.f + expf(-(acc[1] + bias)));
        o.z = 1.f / (1.f + expf(-(acc[2] + bias)));
        o.w = 1.f / (1.f + expf(-(acc[3] + bias)));
        *(float4*)&mask[(((size_t)b * 9 + (t - 18)) * HH + ho) * WW + pst] = o;
    }
}

// ---------------------------------------------------------------------------
// Kernel 2: deformable conv with LDS-window gather.
//  - async-DMA a 7x40-pixel xh window (35.8KB) into LDS (global_load_lds w=16)
//  - overlap DMA with phase-1 param computation; one vmcnt(0)+barrier
//  - gather = ds_read_b64 from window (global fallback for |off|>=2, rare)
//  - phase 3 unchanged: wave owns 16 co, ds_read A + MFMA
#define MPB 32
__global__ __launch_bounds__(512) void k_deform(const short* __restrict__ xh,
                                                const float* __restrict__ off,
                                                const float* __restrict__ mask,
                                                const short* __restrict__ wt2,
                                                const float* __restrict__ bd,
                                                float* __restrict__ y,
                                                float* __restrict__ gstat) {
    __shared__ short     W[WROWS * WCOLS * CIN];  // 35840 B window
    __shared__ short     val[MPB * CKP];          // 37376 B
    __shared__ unsigned  s_yx[MPB * 9];           // 1152 B
    __shared__ _Float16  s_wh[MPB * 9 * 4];       // 2304 B
    // total 76672 B -> 2 blocks/CU

    const int bid  = blockIdx.x;
    const int swz  = (bid & 7) * 256 + (bid >> 3);     // XCD-chunked
    const int pos0 = swz * MPB;
    const int b   = pos0 >> 12;
    const int ho  = (pos0 >> 6) & 63;
    const int wo0 = pos0 & 63;
    const int tid = threadIdx.x;
    const int wv   = tid >> 6;
    const int lane = tid & 63;

    const int s  = min(max(ho - 3, 0), 57);     // window row origin
    const int sc = min(max(wo0 - 3, 0), 24);    // window col origin

    // ---- issue async window DMA (fire-and-forget, compiler can't serialize) ----
    {
        const short* wsrc = xh + (size_t)b * HW * CIN + ((size_t)(s * 64 + sc)) * 64;
        for (int c = wv; c < NCHUNK; c += 8) {
            int r = c / 5, j = c - r * 5;
            const short* src = wsrc + r * 4096 + j * 512 + lane * 8;  // 16B/lane, contiguous
            GLOAD_LDS16(src, &W[c * 512]);
        }
    }

    // ---- phase 1: sampling params (overlaps DMA) ----
    if (tid < MPB * 9) {
        int k = tid >> 5;
        int p = tid & 31;
        int wo = wo0 + p;
        float dy = off[(((size_t)b * 18 + 2 * k    ) * HH + ho) * WW + wo];
        float dx = off[(((size_t)b * 18 + 2 * k + 1) * HH + ho) * WW + wo];
        float m  = mask[(((size_t)b * 9 + k) * HH + ho) * WW + wo];
        float py = (float)(ho - 1 + k / 3) + dy;
        float px = (float)(wo - 1 + k % 3) + dx;
        float fy = floorf(py), fx = floorf(px);
        float ly = py - fy, lx = px - fx;
        int y0 = (int)fy, x0 = (int)fx;
        int y1 = y0 + 1, x1 = x0 + 1;
        float vy0 = ((unsigned)y0 < 64u) ? 1.f : 0.f;
        float vy1 = ((unsigned)y1 < 64u) ? 1.f : 0.f;
        float vx0 = ((unsigned)x0 < 64u) ? 1.f : 0.f;
        float vx1 = ((unsigned)x1 < 64u) ? 1.f : 0.f;
        int y0c = min(max(y0, 0), 63), y1c = min(max(y1, 0), 63);
        int x0c = min(max(x0, 0), 63), x1c = min(max(x1, 0), 63);
        int tt = p * 9 + k;
        s_yx[tt] = (unsigned)y0c | ((unsigned)y1c << 8) | ((unsigned)x0c << 16) | ((unsigned)x1c << 24);
        s_wh[tt * 4 + 0] = (_Float16)((1.f - ly) * (1.f - lx) * m * vy0 * vx0);
        s_wh[tt * 4 + 1] = (_Float16)((1.f - ly) * lx * m * vy0 * vx1);
        s_wh[tt * 4 + 2] = (_Float16)(ly * (1.f - lx) * m * vy1 * vx0);
        s_wh[tt * 4 + 3] = (_Float16)(ly * lx * m * vy1 * vx1);
    }

    asm volatile("s_waitcnt vmcnt(0)" ::: "memory");   // DMA + param loads done
    __syncthreads();

    // ---- phase 2: gather from LDS window (ds_read_b64), blend, write val ----
    {
        const int g  = tid >> 4;            // 0..31 tap-groups
        const int li = tid & 15;
        const int c0 = li * 4;
        const short* xb = xh + (size_t)b * HW * CIN;
        for (int it = 0; it < 9; ++it) {
            int pr = it * 32 + g;
            unsigned yx = s_yx[pr];
            int y0 = yx & 255, y1 = (yx >> 8) & 255;
            int x0 = (yx >> 16) & 255, x1 = yx >> 24;
            float w0 = (float)s_wh[pr * 4 + 0], w1 = (float)s_wh[pr * 4 + 1];
            float w2 = (float)s_wh[pr * 4 + 2], w3 = (float)s_wh[pr * 4 + 3];
            short4v v00, v01, v10, v11;
            bool inw = (y0 >= s) & (y1 <= s + WROWS - 1) & (x0 >= sc) & (x1 <= sc + WCOLS - 1);
            if (inw) {
                int ry0 = (y0 - s) * WCOLS, ry1 = (y1 - s) * WCOLS;
                int cx0 = x0 - sc, cx1 = x1 - sc;
                v00 = *(const short4v*)&W[((ry0 + cx0) << 6) + c0];
                v01 = *(const short4v*)&W[((ry0 + cx1) << 6) + c0];
                v10 = *(const short4v*)&W[((ry1 + cx0) << 6) + c0];
                v11 = *(const short4v*)&W[((ry1 + cx1) << 6) + c0];
            } else {                                   // rare: |offset| >= 2
                v00 = *(const short4v*)&xb[(((y0 << 6) + x0) << 6) + c0];
                v01 = *(const short4v*)&xb[(((y0 << 6) + x1) << 6) + c0];
                v10 = *(const short4v*)&xb[(((y1 << 6) + x0) << 6) + c0];
                v11 = *(const short4v*)&xb[(((y1 << 6) + x1) << 6) + c0];
            }
            int p = pr / 9, k = pr - p * 9;
            short4v o;
#pragma unroll
            for (int j = 0; j < 4; ++j) {
                float f = w0 * bf2f(v00[j]) + w1 * bf2f(v01[j])
                        + w2 * bf2f(v10[j]) + w3 * bf2f(v11[j]);
                o[j] = f2bf(f);
            }
            *(short4v*)&val[p * CKP + (k << 6) + c0] = o;
        }
    }
    __syncthreads();

    // ---- phase 3: wave owns co = wv*16..+15; B from L2, A from val ----
    const int l15  = lane & 15;
    const int lk   = lane >> 4;
    const int co   = wv * 16 + l15;

    short8 br[18];
    {
        const short* wq = wt2 + (size_t)co * 32 + lk * 8;
#pragma unroll
        for (int kc = 0; kc < 18; ++kc)
            br[kc] = *(const short8*)&wq[kc * 4096];
    }

    f32x4 acc0 = (f32x4)(0.f);
    f32x4 acc1 = (f32x4)(0.f);
    const int arow = l15 * CKP + lk * 8;
#pragma unroll
    for (int kc = 0; kc < 18; ++kc) {
        short8 a0 = *(const short8*)&val[arow + kc * 32];
        short8 a1 = *(const short8*)&val[arow + 16 * CKP + kc * 32];
        acc0 = __builtin_amdgcn_mfma_f32_16x16x32_bf16(a0, br[kc], acc0, 0, 0, 0);
        acc1 = __builtin_amdgcn_mfma_f32_16x16x32_bf16(a1, br[kc], acc1, 0, 0, 0);
    }

    // epilogue: y writes (+bias) and fused BN partials
    {
        float bias = bd[co];
        float4 o;
        o.x = acc0[0] + bias; o.y = acc0[1] + bias;
        o.z = acc0[2] + bias; o.w = acc0[3] + bias;
        *(float4*)&y[((size_t)(b * COUT + co)) * HW + ho * WW + wo0 + lk * 4] = o;
        o.x = acc1[0] + bias; o.y = acc1[1] + bias;
        o.z = acc1[2] + bias; o.w = acc1[3] + bias;
        *(float4*)&y[((size_t)(b * COUT + co)) * HW + ho * WW + wo0 + 16 + lk * 4] = o;
    }
    float ls = acc0[0] + acc0[1] + acc0[2] + acc0[3]
             + acc1[0] + acc1[1] + acc1[2] + acc1[3];
    float lq = acc0[0]*acc0[0] + acc0[1]*acc0[1] + acc0[2]*acc0[2] + acc0[3]*acc0[3]
             + acc1[0]*acc1[0] + acc1[1]*acc1[1] + acc1[2]*acc1[2] + acc1[3]*acc1[3];
    ls += __shfl_xor(ls, 16); ls += __shfl_xor(ls, 32);
    lq += __shfl_xor(lq, 16); lq += __shfl_xor(lq, 32);
    if (lane < 16) {
        atomicAdd(&gstat[wv * 16 + lane],       ls);
        atomicAdd(&gstat[128 + wv * 16 + lane], lq);
    }
}

// ---------------------------------------------------------------------------
// Kernel 3: finalize BN scale/shift
__global__ __launch_bounds__(128) void k_finalize(const float* __restrict__ gstat,
                                                  const float* __restrict__ bd,
                                                  const float* __restrict__ gamma,
                                                  const float* __restrict__ beta,
                                                  float* __restrict__ sAB) {
    int c = threadIdx.x;
    const float invN = 1.f / (float)(BB * HW);
    float mean_acc = gstat[c] * invN;
    float var = gstat[128 + c] * invN - mean_acc * mean_acc;
    float mean_y = mean_acc + bd[c];
    float A = gamma[c] * rsqrtf(var + 1e-5f);
    sAB[c]       = A;
    sAB[128 + c] = beta[c] - mean_y * A;
}

// ---------------------------------------------------------------------------
// Kernel 4: normalize + exact GELU (in-place on d_out)
__global__ __launch_bounds__(256) void k_norm_gelu(float* __restrict__ y,
                                                   const float* __restrict__ sAB) {
    int i4 = blockIdx.x * 256 + threadIdx.x;
    if (i4 >= (BB * COUT * HW) / 4) return;
    int c = (i4 >> 10) & 127;
    float A  = sAB[c];
    float Bc = sAB[128 + c];
    float4 v = ((const float4*)y)[i4];
    float4 r;
    float t;
    t = v.x * A + Bc; r.x = 0.5f * t * (1.f + erff(t * 0.70710678118654752f));
    t = v.y * A + Bc; r.y = 0.5f * t * (1.f + erff(t * 0.70710678118654752f));
    t = v.z * A + Bc; r.z = 0.5f * t * (1.f + erff(t * 0.70710678118654752f));
    t = v.w * A + Bc; r.w = 0.5f * t * (1.f + erff(t * 0.70710678118654752f));
    ((float4*)y)[i4] = r;
}

// ---------------------------------------------------------------------------
extern "C" void kernel_launch(void* const* d_in, const int* in_sizes, int n_in,
                              void* d_out, int out_size, void* d_ws, size_t ws_size,
                              hipStream_t stream) {
    const float* x     = (const float*)d_in[0];
    const float* w_p   = (const float*)d_in[1];
    const float* b_p   = (const float*)d_in[2];
    const float* w_m   = (const float*)d_in[3];
    const float* b_m   = (const float*)d_in[4];
    const float* w_d   = (const float*)d_in[5];
    const float* b_d   = (const float*)d_in[6];
    const float* gamma = (const float*)d_in[7];
    const float* beta  = (const float*)d_in[8];
    float* ws  = (float*)d_ws;
    float* y   = (float*)d_out;

    float* off  = ws + OFF_OFF;
    float* mask = ws + MASK_OFF;
    short* wt2  = (short*)(ws + WT_OFF);
    short* wpm2 = (short*)(ws + WPM_OFF);
    short* xh   = (short*)(ws + XH_OFF);
    float* sAB  = ws + SAB_OFF;
    float* gstat= ws + STAT_OFF;

    hipMemsetAsync(gstat, 0, 256 * sizeof(float), stream);
    k_nhwc<<<dim3(1024), dim3(256), 0, stream>>>(x, xh);
    k_pack<<<dim3((18 * 128 * 32 + 18 * 32 * 32) / 256), dim3(256), 0, stream>>>(w_d, w_p, w_m, wt2, wpm2);
    k_conv_pm<<<dim3(BB * HW / 32), dim3(256), 0, stream>>>(xh, wpm2, b_p, b_m, off, mask);
    k_deform<<<dim3(BB * HW / MPB), dim3(512), 0, stream>>>(xh, off, mask, wt2, b_d, y, gstat);
    k_finalize<<<dim3(1), dim3(128), 0, stream>>>(gstat, b_d, gamma, beta, sAB);
    k_norm_gelu<<<dim3((BB * COUT * HW / 4 + 255) / 256), dim3(256), 0, stream>>>(y, sAB);
}

// Round 10
// 110.044 us; speedup vs baseline: 1.1356x; 1.1356x over previous
//
#include <hip/hip_runtime.h>
#include <math.h>

#define BB 16
#define CIN 64
#define HH 64
#define WW 64
#define COUT 128
#define HW 4096          // HH*WW
#define CK 576           // CIN*9
#define CKP 584          // LDS stride (shorts) for val

typedef __attribute__((ext_vector_type(8))) short short8;
typedef __attribute__((ext_vector_type(4))) short short4v;
typedef __attribute__((ext_vector_type(4))) float f32x4;

// keep a loaded value live in VGPRs — blocks rematerialization/sinking
#define PIN(x) asm volatile("" : "+v"(x))

// ---- workspace layout (float indices) ----
#define OFF_OFF   0                         // B*18*HW  = 1179648 floats
#define MASK_OFF  1179648                   // B*9*HW   = 589824 floats
#define WT_OFF    1769472                   // wt2: 18*128*32 shorts = 36864 floats
#define WPM_OFF   1806336                   // wpm2: 18*32*32 shorts = 9216 floats
#define XH_OFF    1815552                   // B*HW*CIN shorts = 8388608 floats
#define SAB_OFF   10204160                  // 256 floats
#define STAT_OFF  10204416                  // 64 slots * 256 floats = 16384

__device__ __forceinline__ short f2bf(float f) {
    union { float f; unsigned u; } cv; cv.f = f;
    unsigned u = cv.u;
    unsigned r = (u + 0x7fffu + ((u >> 16) & 1u)) >> 16;
    return (short)r;
}
__device__ __forceinline__ float bf2f(short s) {
    union { unsigned u; float f; } cv;
    cv.u = ((unsigned)(unsigned short)s) << 16;
    return cv.f;
}
__device__ __forceinline__ unsigned cvt_pk_bf16(float lo, float hi) {
    unsigned r;
    asm("v_cvt_pk_bf16_f32 %0, %1, %2" : "=v"(r) : "v"(lo), "v"(hi));
    return r;
}

// ---------------------------------------------------------------------------
// Kernel A: transpose x NCHW -> NHWC bf16 (xh[b][y][x][c])
__global__ __launch_bounds__(256) void k_nhwc(const float* __restrict__ x,
                                              short* __restrict__ xh) {
    __shared__ float t[64][65];
    const int blk  = blockIdx.x;
    const int b    = blk >> 6;
    const int pos0 = (blk & 63) << 6;
    const int a    = threadIdx.x & 63;
    const int q    = threadIdx.x >> 6;
#pragma unroll
    for (int i = 0; i < 16; ++i) {
        int c = i * 4 + q;
        t[c][a] = x[((size_t)(b * CIN + c)) * HW + pos0 + a];
    }
    __syncthreads();
#pragma unroll
    for (int i = 0; i < 16; ++i) {
        int p = i * 4 + q;
        xh[((size_t)b * HW + pos0 + p) * CIN + a] = f2bf(t[a][p]);
    }
}

// ---------------------------------------------------------------------------
// Kernel B: pack weights to bf16, K-MAJOR panels.
__global__ __launch_bounds__(256) void k_pack(const float* __restrict__ wd,
                                              const float* __restrict__ wp,
                                              const float* __restrict__ wm,
                                              short* __restrict__ wt2,
                                              short* __restrict__ wpm2) {
    int i = blockIdx.x * 256 + threadIdx.x;
    if (i < 18 * 128 * 32) {
        int kc  = i >> 12;
        int rem = i & 4095;
        int co  = rem >> 5;
        int kl  = rem & 31;
        int kk  = kc * 32 + kl;
        int k   = kk >> 6;
        int c   = kk & 63;
        wt2[i] = f2bf(wd[co * CK + c * 9 + k]);
        return;
    }
    i -= 18 * 128 * 32;
    if (i < 18 * 32 * 32) {
        int kc  = i >> 10;
        int rem = i & 1023;
        int t   = rem >> 5;
        int kl  = rem & 31;
        int kk  = kc * 32 + kl;
        int k   = kk >> 6;
        int c   = kk & 63;
        float v = 0.f;
        if (t < 18)      v = wp[t * CK + c * 9 + k];
        else if (t < 27) v = wm[(t - 18) * CK + c * 9 + k];
        wpm2[i] = f2bf(v);
    }
}

// ---------------------------------------------------------------------------
// conv_pm A-fragment loader
__device__ __forceinline__ short8 conv_a(const short* __restrict__ xb,
                                         int ho, int wo, int lk, int kc) {
    const int k  = kc >> 1;
    const int c0 = (kc & 1) * 32 + lk * 8;
    const int yy = ho - 1 + k / 3;
    const int xx = wo - 1 + k % 3;
    const bool valid = ((unsigned)yy < 64u) & ((unsigned)xx < 64u);
    const int yyc = min(max(yy, 0), 63);
    const int xxc = min(max(xx, 0), 63);
    short8 a = *(const short8*)&xb[(((yyc << 6) + xxc) << 6) + c0];
    if (!valid) a = (short8)0;
    return a;
}

// ---------------------------------------------------------------------------
// Kernel 1: offset/mask conv — depth-6 PINNED rings for A and B fragments.
__global__ __launch_bounds__(256) void k_conv_pm(const short* __restrict__ xh,
                                                 const short* __restrict__ wpm2,
                                                 const float* __restrict__ bp,
                                                 const float* __restrict__ bm,
                                                 float* __restrict__ off,
                                                 float* __restrict__ mask) {
    const int bid  = blockIdx.x;
    const int swz  = (bid & 7) * 256 + (bid >> 3);
    const int pos0 = swz * 32;
    const int b   = pos0 >> 12;
    const int ho  = (pos0 >> 6) & 63;
    const int wo0 = pos0 & 63;

    const int tid  = threadIdx.x;
    const int wv   = tid >> 6;
    const int lane = tid & 63;
    const int l15  = lane & 15;
    const int lk   = lane >> 4;
    const int mw   = wv & 1;
    const int nw   = wv >> 1;

    const int p    = mw * 16 + l15;
    const int wo   = wo0 + p;
    const int t    = nw * 16 + l15;

    const short* xb  = xh + (size_t)b * HW * CIN;
    const short* wr  = wpm2 + t * 32 + lk * 8;

    short8 ar[6], brr[6];
#pragma unroll
    for (int i = 0; i < 6; ++i) {
        ar[i]  = conv_a(xb, ho, wo, lk, i);    PIN(ar[i]);
        brr[i] = *(const short8*)&wr[i * 1024]; PIN(brr[i]);
    }
    f32x4 acc = (f32x4)(0.f);
#pragma unroll
    for (int kc = 0; kc < 18; ++kc) {
        acc = __builtin_amdgcn_mfma_f32_16x16x32_bf16(ar[kc % 6], brr[kc % 6], acc, 0, 0, 0);
        if (kc + 6 < 18) {
            ar[kc % 6]  = conv_a(xb, ho, wo, lk, kc + 6);        PIN(ar[kc % 6]);
            brr[kc % 6] = *(const short8*)&wr[(kc + 6) * 1024];  PIN(brr[kc % 6]);
        }
    }

    const int pst = wo0 + mw * 16 + lk * 4;
    if (t < 18) {
        float bias = bp[t];
        float4 o;
        o.x = acc[0] + bias; o.y = acc[1] + bias;
        o.z = acc[2] + bias; o.w = acc[3] + bias;
        *(float4*)&off[(((size_t)b * 18 + t) * HH + ho) * WW + pst] = o;
    } else if (t < 27) {
        float bias = bm[t - 18];
        float4 o;
        o.x = 1.f / (1.f + expf(-(acc[0] + bias)));
        o.y = 1.f / (1.f + expf(-(acc[1] + bias)));
        o.z = 1.f / (1.f + expf(-(acc[2] + bias)));
        o.w = 1.f / (1.f + expf(-(acc[3] + bias)));
        *(float4*)&mask[(((size_t)b * 9 + (t - 18)) * HH + ho) * WW + pst] = o;
    }
}

// ---------------------------------------------------------------------------
// Kernel 2: deformable conv. 512 threads. Pinned-register pipelines:
//  phase 2: 3-tap batches, double-buffered, corner loads pinned.
//  phase 3: depth-6 pinned B-ring; A from LDS; wave owns 16 co.
//  BN partials -> 64-slot spread atomics.
#define MPB 32
__global__ __launch_bounds__(512) void k_deform(const short* __restrict__ xh,
                                                const float* __restrict__ off,
                                                const float* __restrict__ mask,
                                                const short* __restrict__ wt2,
                                                const float* __restrict__ bd,
                                                float* __restrict__ y,
                                                float* __restrict__ gstat) {
    __shared__ short     val[MPB * CKP];    // 37376 B
    __shared__ unsigned  s_yx[MPB * 9];     // 1152 B
    __shared__ _Float16  s_wh[MPB * 9 * 4]; // 2304 B -> 40832 B total

    const int bid  = blockIdx.x;
    const int swz  = (bid & 7) * 256 + (bid >> 3);     // XCD-chunked
    const int pos0 = swz * MPB;
    const int b   = pos0 >> 12;
    const int ho  = (pos0 >> 6) & 63;
    const int wo0 = pos0 & 63;
    const int tid = threadIdx.x;
    const int wv   = tid >> 6;
    const int lane = tid & 63;

    // ---- phase 1: sampling params ----
    if (tid < MPB * 9) {
        int k = tid >> 5;
        int p = tid & 31;
        int wo = wo0 + p;
        float dy = off[(((size_t)b * 18 + 2 * k    ) * HH + ho) * WW + wo];
        float dx = off[(((size_t)b * 18 + 2 * k + 1) * HH + ho) * WW + wo];
        float m  = mask[(((size_t)b * 9 + k) * HH + ho) * WW + wo];
        float py = (float)(ho - 1 + k / 3) + dy;
        float px = (float)(wo - 1 + k % 3) + dx;
        float fy = floorf(py), fx = floorf(px);
        float ly = py - fy, lx = px - fx;
        int y0 = (int)fy, x0 = (int)fx;
        int y1 = y0 + 1, x1 = x0 + 1;
        float vy0 = ((unsigned)y0 < 64u) ? 1.f : 0.f;
        float vy1 = ((unsigned)y1 < 64u) ? 1.f : 0.f;
        float vx0 = ((unsigned)x0 < 64u) ? 1.f : 0.f;
        float vx1 = ((unsigned)x1 < 64u) ? 1.f : 0.f;
        int y0c = min(max(y0, 0), 63), y1c = min(max(y1, 0), 63);
        int x0c = min(max(x0, 0), 63), x1c = min(max(x1, 0), 63);
        int tt = p * 9 + k;
        s_yx[tt] = (unsigned)y0c | ((unsigned)y1c << 8) | ((unsigned)x0c << 16) | ((unsigned)x1c << 24);
        s_wh[tt * 4 + 0] = (_Float16)((1.f - ly) * (1.f - lx) * m * vy0 * vx0);
        s_wh[tt * 4 + 1] = (_Float16)((1.f - ly) * lx * m * vy0 * vx1);
        s_wh[tt * 4 + 2] = (_Float16)(ly * (1.f - lx) * m * vy1 * vx0);
        s_wh[tt * 4 + 3] = (_Float16)(ly * lx * m * vy1 * vx1);
    }
    __syncthreads();

    // ---- phase 2: gather, 3-tap pinned batches, double-buffered ----
    {
        const int g  = tid >> 4;            // 0..31 tap-groups
        const int li = tid & 15;
        const int c0 = li * 4;
        const short* xb = xh + (size_t)b * HW * CIN;

        short4v va[3][4], vb[3][4];

#define GLOAD_BATCH(buf, IT0)                                                   \
        _Pragma("unroll")                                                       \
        for (int s3 = 0; s3 < 3; ++s3) {                                        \
            int pr = (IT0 + s3) * 32 + g;                                       \
            unsigned yx = s_yx[pr];                                             \
            int gy0 = yx & 255, gy1 = (yx >> 8) & 255;                          \
            int gx0 = (yx >> 16) & 255, gx1 = yx >> 24;                         \
            buf[s3][0] = *(const short4v*)&xb[(((gy0 << 6) + gx0) << 6) + c0]; PIN(buf[s3][0]); \
            buf[s3][1] = *(const short4v*)&xb[(((gy0 << 6) + gx1) << 6) + c0]; PIN(buf[s3][1]); \
            buf[s3][2] = *(const short4v*)&xb[(((gy1 << 6) + gx0) << 6) + c0]; PIN(buf[s3][2]); \
            buf[s3][3] = *(const short4v*)&xb[(((gy1 << 6) + gx1) << 6) + c0]; PIN(buf[s3][3]); \
        }

#define BLEND_BATCH(buf, IT0)                                                   \
        _Pragma("unroll")                                                       \
        for (int s3 = 0; s3 < 3; ++s3) {                                        \
            int pr = (IT0 + s3) * 32 + g;                                       \
            int p = pr / 9, k = pr - p * 9;                                     \
            float w0 = (float)s_wh[pr * 4 + 0], w1 = (float)s_wh[pr * 4 + 1];   \
            float w2 = (float)s_wh[pr * 4 + 2], w3 = (float)s_wh[pr * 4 + 3];   \
            float f0 = w0*bf2f(buf[s3][0][0]) + w1*bf2f(buf[s3][1][0])          \
                     + w2*bf2f(buf[s3][2][0]) + w3*bf2f(buf[s3][3][0]);         \
            float f1 = w0*bf2f(buf[s3][0][1]) + w1*bf2f(buf[s3][1][1])          \
                     + w2*bf2f(buf[s3][2][1]) + w3*bf2f(buf[s3][3][1]);         \
            float f2 = w0*bf2f(buf[s3][0][2]) + w1*bf2f(buf[s3][1][2])          \
                     + w2*bf2f(buf[s3][2][2]) + w3*bf2f(buf[s3][3][2]);         \
            float f3 = w0*bf2f(buf[s3][0][3]) + w1*bf2f(buf[s3][1][3])          \
                     + w2*bf2f(buf[s3][2][3]) + w3*bf2f(buf[s3][3][3]);         \
            union { unsigned u[2]; short4v s; } pk;                             \
            pk.u[0] = cvt_pk_bf16(f0, f1);                                      \
            pk.u[1] = cvt_pk_bf16(f2, f3);                                      \
            *(short4v*)&val[p * CKP + (k << 6) + c0] = pk.s;                    \
        }

        GLOAD_BATCH(va, 0)
        GLOAD_BATCH(vb, 3)
        BLEND_BATCH(va, 0)
        GLOAD_BATCH(va, 6)
        BLEND_BATCH(vb, 3)
        BLEND_BATCH(va, 6)
#undef GLOAD_BATCH
#undef BLEND_BATCH
    }
    __syncthreads();

    // ---- phase 3: wave owns co = wv*16..+15; depth-6 pinned B-ring ----
    const int l15  = lane & 15;
    const int lk   = lane >> 4;
    const int co   = wv * 16 + l15;
    const short* wq = wt2 + (size_t)co * 32 + lk * 8;

    short8 br[6];
#pragma unroll
    for (int i = 0; i < 6; ++i) {
        br[i] = *(const short8*)&wq[i * 4096]; PIN(br[i]);
    }

    f32x4 acc0 = (f32x4)(0.f);
    f32x4 acc1 = (f32x4)(0.f);
    const int arow = l15 * CKP + lk * 8;
#pragma unroll
    for (int kc = 0; kc < 18; ++kc) {
        short8 a0 = *(const short8*)&val[arow + kc * 32];
        short8 a1 = *(const short8*)&val[arow + 16 * CKP + kc * 32];
        acc0 = __builtin_amdgcn_mfma_f32_16x16x32_bf16(a0, br[kc % 6], acc0, 0, 0, 0);
        acc1 = __builtin_amdgcn_mfma_f32_16x16x32_bf16(a1, br[kc % 6], acc1, 0, 0, 0);
        if (kc + 6 < 18) {
            br[kc % 6] = *(const short8*)&wq[(kc + 6) * 4096]; PIN(br[kc % 6]);
        }
    }

    // epilogue: y writes (+bias) and BN partials to 64-slot spread
    {
        float bias = bd[co];
        float4 o;
        o.x = acc0[0] + bias; o.y = acc0[1] + bias;
        o.z = acc0[2] + bias; o.w = acc0[3] + bias;
        *(float4*)&y[((size_t)(b * COUT + co)) * HW + ho * WW + wo0 + lk * 4] = o;
        o.x = acc1[0] + bias; o.y = acc1[1] + bias;
        o.z = acc1[2] + bias; o.w = acc1[3] + bias;
        *(float4*)&y[((size_t)(b * COUT + co)) * HW + ho * WW + wo0 + 16 + lk * 4] = o;
    }
    float ls = acc0[0] + acc0[1] + acc0[2] + acc0[3]
             + acc1[0] + acc1[1] + acc1[2] + acc1[3];
    float lq = acc0[0]*acc0[0] + acc0[1]*acc0[1] + acc0[2]*acc0[2] + acc0[3]*acc0[3]
             + acc1[0]*acc1[0] + acc1[1]*acc1[1] + acc1[2]*acc1[2] + acc1[3]*acc1[3];
    ls += __shfl_xor(ls, 16); ls += __shfl_xor(ls, 32);
    lq += __shfl_xor(lq, 16); lq += __shfl_xor(lq, 32);
    if (lane < 16) {
        float* slot = gstat + (bid & 63) * 256;
        atomicAdd(&slot[wv * 16 + lane],       ls);
        atomicAdd(&slot[128 + wv * 16 + lane], lq);
    }
}

// ---------------------------------------------------------------------------
// Kernel 3: finalize BN scale/shift (reduce 64 slots)
__global__ __launch_bounds__(128) void k_finalize(const float* __restrict__ gstat,
                                                  const float* __restrict__ bd,
                                                  const float* __restrict__ gamma,
                                                  const float* __restrict__ beta,
                                                  float* __restrict__ sAB) {
    int c = threadIdx.x;
    float s = 0.f, q = 0.f;
    for (int sl = 0; sl < 64; ++sl) {
        s += gstat[sl * 256 + c];
        q += gstat[sl * 256 + 128 + c];
    }
    const float invN = 1.f / (float)(BB * HW);
    float mean_acc = s * invN;
    float var = q * invN - mean_acc * mean_acc;
    float mean_y = mean_acc + bd[c];
    float A = gamma[c] * rsqrtf(var + 1e-5f);
    sAB[c]       = A;
    sAB[128 + c] = beta[c] - mean_y * A;
}

// ---------------------------------------------------------------------------
// Kernel 4: normalize + exact GELU (in-place on d_out)
__global__ __launch_bounds__(256) void k_norm_gelu(float* __restrict__ y,
                                                   const float* __restrict__ sAB) {
    int i4 = blockIdx.x * 256 + threadIdx.x;
    if (i4 >= (BB * COUT * HW) / 4) return;
    int c = (i4 >> 10) & 127;
    float A  = sAB[c];
    float Bc = sAB[128 + c];
    float4 v = ((const float4*)y)[i4];
    float4 r;
    float t;
    t = v.x * A + Bc; r.x = 0.5f * t * (1.f + erff(t * 0.70710678118654752f));
    t = v.y * A + Bc; r.y = 0.5f * t * (1.f + erff(t * 0.70710678118654752f));
    t = v.z * A + Bc; r.z = 0.5f * t * (1.f + erff(t * 0.70710678118654752f));
    t = v.w * A + Bc; r.w = 0.5f * t * (1.f + erff(t * 0.70710678118654752f));
    ((float4*)y)[i4] = r;
}

// ---------------------------------------------------------------------------
extern "C" void kernel_launch(void* const* d_in, const int* in_sizes, int n_in,
                              void* d_out, int out_size, void* d_ws, size_t ws_size,
                              hipStream_t stream) {
    const float* x     = (const float*)d_in[0];
    const float* w_p   = (const float*)d_in[1];
    const float* b_p   = (const float*)d_in[2];
    const float* w_m   = (const float*)d_in[3];
    const float* b_m   = (const float*)d_in[4];
    const float* w_d   = (const float*)d_in[5];
    const float* b_d   = (const float*)d_in[6];
    const float* gamma = (const float*)d_in[7];
    const float* beta  = (const float*)d_in[8];
    float* ws  = (float*)d_ws;
    float* y   = (float*)d_out;

    float* off  = ws + OFF_OFF;
    float* mask = ws + MASK_OFF;
    short* wt2  = (short*)(ws + WT_OFF);
    short* wpm2 = (short*)(ws + WPM_OFF);
    short* xh   = (short*)(ws + XH_OFF);
    float* sAB  = ws + SAB_OFF;
    float* gstat= ws + STAT_OFF;

    hipMemsetAsync(gstat, 0, 64 * 256 * sizeof(float), stream);
    k_nhwc<<<dim3(1024), dim3(256), 0, stream>>>(x, xh);
    k_pack<<<dim3((18 * 128 * 32 + 18 * 32 * 32) / 256), dim3(256), 0, stream>>>(w_d, w_p, w_m, wt2, wpm2);
    k_conv_pm<<<dim3(BB * HW / 32), dim3(256), 0, stream>>>(xh, wpm2, b_p, b_m, off, mask);
    k_deform<<<dim3(BB * HW / MPB), dim3(512), 0, stream>>>(xh, off, mask, wt2, b_d, y, gstat);
    k_finalize<<<dim3(1), dim3(128), 0, stream>>>(gstat, b_d, gamma, beta, sAB);
    k_norm_gelu<<<dim3((BB * COUT * HW / 4 + 255) / 256), dim3(256), 0, stream>>>(y, sAB);
}